// Round 1
// baseline (9.881 us; speedup 1.0000x reference)
//
#include <hip/hip_runtime.h>
#include <cfloat>
#include <cmath>

// Reference reduces to, per (batch b, channel ch):
//   anded[t] = -|c[t]| - log1p(exp(-2*AND_SCALE*|c[t]|)) / AND_SCALE
//   out[t]   = max_{j >= t} anded[j]        (suffix max)
// because eventually_trace's masked maxish over rows r in [t, t+T] of
// padded = [anded, repeat(anded[T-1])] is exactly a suffix max (the
// EV_SCALE=1e9 logsumexp tie-correction is <= log(2T+1)/1e9 ~ 7.6e-9).
//
// T = 1024, B = 32, 2 channels. One block per batch; both channels
// scanned simultaneously via Hillis-Steele suffix-max in LDS.

__global__ __launch_bounds__(1024) void stl_suffix_kernel(
    const float* __restrict__ sig,   // (B, T, 2) row-major
    float* __restrict__ out,         // (2, B, T): final then final_2
    int B, int T)
{
    const int b = blockIdx.x;
    const int t = threadIdx.x;

    __shared__ float sx[1024];
    __shared__ float sy[1024];

    // Coalesced 8B load: both channels of element (b, t).
    float2 v = reinterpret_cast<const float2*>(sig)[b * T + t];

    const float AND_SCALE = 100000.0f;
    float ax = fabsf(v.x);
    float ay = fabsf(v.y);
    // smooth-min of (c, -c): exact stable form of -logsumexp([-c*s, c*s])/s
    float vx = -ax - log1pf(expf(-2.0f * AND_SCALE * ax)) / AND_SCALE;
    float vy = -ay - log1pf(expf(-2.0f * AND_SCALE * ay)) / AND_SCALE;

    sx[t] = vx;
    sy[t] = vy;
    __syncthreads();

    // Hillis-Steele inclusive suffix-max scan (10 steps for T=1024).
    #pragma unroll
    for (int st = 1; st < 1024; st <<= 1) {
        float ox = (t + st < 1024) ? sx[t + st] : -FLT_MAX;
        float oy = (t + st < 1024) ? sy[t + st] : -FLT_MAX;
        __syncthreads();
        sx[t] = fmaxf(sx[t], ox);
        sy[t] = fmaxf(sy[t], oy);
        __syncthreads();
    }

    // final (channel 0) occupies out[0 .. B*T), final_2 follows.
    out[b * T + t]          = sx[t];
    out[B * T + b * T + t]  = sy[t];
}

extern "C" void kernel_launch(void* const* d_in, const int* in_sizes, int n_in,
                              void* d_out, int out_size, void* d_ws, size_t ws_size,
                              hipStream_t stream) {
    const float* sig = (const float*)d_in[0];
    float* out = (float*)d_out;
    const int T = 1024;
    const int B = in_sizes[0] / (T * 2);   // 32 for the given setup
    stl_suffix_kernel<<<B, T, 0, stream>>>(sig, out, B, T);
}

// Round 2
// 9.591 us; speedup vs baseline: 1.0303x; 1.0303x over previous
//
#include <hip/hip_runtime.h>
#include <cfloat>
#include <cmath>

// Reference reduces to, per (batch b, channel ch):
//   anded[t] = -|c[t]| - log1p(exp(-2e5*|c[t]|))/1e5
//   out[t]   = max_{j >= t} anded[j]          (suffix max)
//
// The log1p correction is bounded by log(2)/1e5 = 6.93e-6 (and is exactly 0
// in fp32 for |c| > 4.5e-4); the harness threshold is 4.875e-2, so we drop
// it: out[t] = -min_{j>=t} |c[j]|. The EV_SCALE=1e9 tie-correction is
// <= log(2T+1)/1e9 ~ 7.6e-9, likewise dropped.
//
// T = 1024, B = 32, 2 channels. One WAVE (64 lanes) per batch; each lane
// owns 16 consecutive t for both channels. In-register serial suffix-max
// (15 fmax/channel) + 6-step __shfl_down wave suffix scan. No LDS, no
// __syncthreads — pure register/shuffle latency path.

__global__ __launch_bounds__(64) void stl_suffix_wave(
    const float* __restrict__ sig,   // (B, T, 2) row-major
    float* __restrict__ out,         // (2, B, T): final then final_2
    int B, int T)
{
    const int b    = blockIdx.x;
    const int lane = threadIdx.x;          // 0..63
    const int t0   = lane * 16;

    // Load 16 interleaved (x,y) pairs = 8 x float4 = 128 B per lane.
    const float4* p = reinterpret_cast<const float4*>(sig) + (size_t)b * (T / 2) + lane * 8;
    float vx[16], vy[16];
    #pragma unroll
    for (int i = 0; i < 8; ++i) {
        float4 q = p[i];                    // (x[2i], y[2i], x[2i+1], y[2i+1])
        vx[2 * i]     = fabsf(q.x);
        vy[2 * i]     = fabsf(q.y);
        vx[2 * i + 1] = fabsf(q.z);
        vy[2 * i + 1] = fabsf(q.w);
    }

    // In-lane suffix-min of |c| (kept as min; negate at the end).
    #pragma unroll
    for (int i = 14; i >= 0; --i) {
        vx[i] = fminf(vx[i], vx[i + 1]);
        vy[i] = fminf(vy[i], vy[i + 1]);
    }

    // Wave-level inclusive suffix-min scan of per-lane totals (vx[0], vy[0]).
    float mx = vx[0], my = vy[0];
    #pragma unroll
    for (int off = 1; off < 64; off <<= 1) {
        float ox = __shfl_down(mx, off);
        float oy = __shfl_down(my, off);
        if (lane + off < 64) { mx = fminf(mx, ox); my = fminf(my, oy); }
    }
    // Exclusive "min over all lanes > me".
    float ex = __shfl_down(mx, 1);
    float ey = __shfl_down(my, 1);
    if (lane == 63) { ex = FLT_MAX; ey = FLT_MAX; }

    #pragma unroll
    for (int i = 0; i < 16; ++i) {
        vx[i] = -fminf(vx[i], ex);
        vy[i] = -fminf(vy[i], ey);
    }

    // Coalesced-per-lane 16B stores: 4 x float4 per channel.
    float4* ox4 = reinterpret_cast<float4*>(out + (size_t)b * T + t0);
    float4* oy4 = reinterpret_cast<float4*>(out + (size_t)B * T + (size_t)b * T + t0);
    #pragma unroll
    for (int i = 0; i < 4; ++i) {
        ox4[i] = make_float4(vx[4 * i], vx[4 * i + 1], vx[4 * i + 2], vx[4 * i + 3]);
        oy4[i] = make_float4(vy[4 * i], vy[4 * i + 1], vy[4 * i + 2], vy[4 * i + 3]);
    }
}

extern "C" void kernel_launch(void* const* d_in, const int* in_sizes, int n_in,
                              void* d_out, int out_size, void* d_ws, size_t ws_size,
                              hipStream_t stream) {
    const float* sig = (const float*)d_in[0];
    float* out = (float*)d_out;
    const int T = 1024;
    const int B = in_sizes[0] / (T * 2);   // 32 for the given setup
    stl_suffix_wave<<<B, 64, 0, stream>>>(sig, out, B, T);
}